// Round 18
// baseline (516.590 us; speedup 1.0000x reference)
//
#include <hip/hip_runtime.h>
#include <math.h>

#define NS 150
#define LDW 152
#define NPACK 11848   // packed upper-tri floats (rows 16B-aligned)
#define NT 40
#define MS 200
#define MT 30
#define N_SWEEPS 6
#define ROUNDS (N_SWEEPS*(NT-1))
#define JITTER 0.1f
#define NTHR 512

// ---- kernel-1 LDS union layout (bytes) ----
#define OFF_MP    0        // 47392
#define OFF_PR    47392    // 8*152*4 = 4864 -> 52256
#define OFF_INVS  52256    // 32 -> 52288
#define OFF_DVS   52288    // 600 -> 52896 (pad)
#define OFF_SCS   52896    // 1800 -> 54704 (pad)
#define OFF_GV    54704    // 600 -> 55304
#define OFF_ACOL  55304    // 120 -> 55424
#define OFF_WTJ   55424    // 4  -> 55428
#define SMEM_BYTES 55440
// jacobi-phase overlay (inside Mp region only):
#define OFF_A2    0        // 2*40*41*4 = 13120
#define OFF_VTS   13120    // 40*44*4 = 7040 -> 20160
#define OFF_PRM   20160    // 8*20*16 = 2560 -> 22720
#define OFF_TCS   22720    // 160 -> 22880   (< OFF_PR; gv/Acol/wtj live above)

// packed upper-tri storage: row r holds cols [r&~3, 152), 16B-aligned start.
__device__ __forceinline__ int rs_off(int r) {
    int g = r >> 2, rm = r & 3;
    return LDW * r - 8 * g * (g - 1) - 4 * rm * g;
}

__device__ __forceinline__ void jac_params(const float (*A)[NT+1], float4* dst,
                                           int i, int rr) {
    int i0 = i, i1 = NT - 1 - i;
    int p = (i0 == 0) ? 0 : ((i0 - 1 + rr) % (NT - 1)) + 1;
    int q = ((i1 - 1 + rr) % (NT - 1)) + 1;
    if (p > q) { int tsw = p; p = q; q = tsw; }
    float app = A[p][p], aqq = A[q][q], apq = A[p][q];
    float c, s;
    if (apq == 0.0f) { c = 1.0f; s = 0.0f; }
    else {
        float tau = (aqq - app) / (2.0f * apq);
        float tt = ((tau >= 0.0f) ? 1.0f : -1.0f) / (fabsf(tau) + sqrtf(1.0f + tau*tau));
        c = rsqrtf(1.0f + tt*tt);
        s = tt * c;
    }
    dst[i] = make_float4(c, s, __int_as_float(p), __int_as_float(q));
}

// K1: 40 blocks x 512 threads (R14/R17-proven core, trsm removed). Per block:
// redundant Jacobi -> extract (wt_j, g_j, Acol_j) -> packed M_j build ->
// rank-8 panel factor -> in-LDS scale (diag=1/d, col150=y) -> write scaled
// packed U to Ug[j] and Acol to AcolG[j].
__global__ void __launch_bounds__(NTHR, 1) gp_factor(
        const float* __restrict__ sc,  const float* __restrict__ tc,
        const float* __restrict__ st,  const float* __restrict__ ttc,
        const float* __restrict__ lll, const float* __restrict__ lle,
        const float* __restrict__ llt, const float* __restrict__ lnv,
        float* __restrict__ Ug, float* __restrict__ AcolG) {
    __shared__ __align__(16) char smem[SMEM_BYTES];
    int j = blockIdx.x, tid = threadIdx.x;

    auto A2   = (float (*)[NT][NT+1])(smem + OFF_A2);
    auto Vts  = (float (*)[44])(smem + OFF_VTS);
    auto prm  = (float4 (*)[NT/2])(smem + OFF_PRM);
    float* tcs  = (float*)(smem + OFF_TCS);
    float* gv   = (float*)(smem + OFF_GV);
    float* Acol = (float*)(smem + OFF_ACOL);
    float* wtjs = (float*)(smem + OFF_WTJ);
    float* scs  = (float*)(smem + OFF_SCS);

    float ilt2 = expf(-2.0f * llt[0]);
    if (tid < NT) tcs[tid] = tc[tid];
    for (int t = tid; t < NS*3; t += NTHR) scs[t] = sc[t];
    __syncthreads();
    for (int idx = tid; idx < NT*NT; idx += NTHR) {
        int i = idx / NT, jj = idx - i*NT;
        float dt = tcs[i] - tcs[jj];
        float v = expf(-dt*dt*ilt2);
        if (i == jj) v += JITTER;
        A2[0][i][jj] = v;
    }
    for (int idx = tid; idx < NT*44; idx += NTHR) {
        int jr = idx / 44, k = idx - jr*44;
        Vts[jr][k] = (jr == k) ? 1.0f : 0.0f;
    }
    __syncthreads();
    int wave = tid >> 6, lane = tid & 63;
    for (int rd = 0; rd < ROUNDS; ++rd) {
        int cur = rd & 1, nxt = cur ^ 1;
        float4* wp = prm[wave];
        if (lane < NT/2) jac_params(A2[cur], wp, lane, rd % (NT - 1));
        __builtin_amdgcn_wave_barrier();   // same-wave LDS in-order; pin compiler
        for (int t = tid; t < 600; t += NTHR) {
            if (t < 400) {
                int bi = t / 20, bj = t - bi*20;
                float4 Pi = wp[bi], Pj = wp[bj];
                int pi = __float_as_int(Pi.z), qi = __float_as_int(Pi.w);
                int pj = __float_as_int(Pj.z), qj = __float_as_int(Pj.w);
                float ci = Pi.x, si = Pi.y, cj = Pj.x, sj = Pj.y;
                float a00 = A2[cur][pi][pj], a01 = A2[cur][pi][qj];
                float a10 = A2[cur][qi][pj], a11 = A2[cur][qi][qj];
                float b00 = ci*a00 - si*a10, b01 = ci*a01 - si*a11;
                float b10 = si*a00 + ci*a10, b11 = si*a01 + ci*a11;
                A2[nxt][pi][pj] = cj*b00 - sj*b01; A2[nxt][pi][qj] = sj*b00 + cj*b01;
                A2[nxt][qi][pj] = cj*b10 - sj*b11; A2[nxt][qi][qj] = sj*b10 + cj*b11;
            } else {
                int u2 = t - 400;
                int pr = u2 / 10, ch = (u2 - pr*10) << 2;
                float4 P = wp[pr];
                int pj = __float_as_int(P.z), qj = __float_as_int(P.w);
                float c = P.x, s = P.y;
                float4 vp = *(float4*)&Vts[pj][ch];
                float4 vq = *(float4*)&Vts[qj][ch];
                float4 np, nq;
                np.x = c*vp.x - s*vq.x; nq.x = s*vp.x + c*vq.x;
                np.y = c*vp.y - s*vq.y; nq.y = s*vp.y + c*vq.y;
                np.z = c*vp.z - s*vq.z; nq.z = s*vp.z + c*vq.z;
                np.w = c*vp.w - s*vq.w; nq.w = s*vp.w + c*vq.w;
                *(float4*)&Vts[pj][ch] = np;
                *(float4*)&Vts[qj][ch] = nq;
            }
        }
        __syncthreads();
    }
    const int fin = ROUNDS & 1;
    if (tid == 0) wtjs[0] = A2[fin][j][j];
    for (int s = tid; s < NS; s += NTHR) {
        const float4* va = (const float4*)&Vts[j][0];
        const float4* sa = (const float4*)&st[s*NT];
        float acc = 0.0f;
        #pragma unroll
        for (int c4 = 0; c4 < NT/4; ++c4) {
            float4 a = va[c4], b = sa[c4];
            acc += a.x*b.x + a.y*b.y + a.z*b.z + a.w*b.w;
        }
        gv[s] = acc;
    }
    if (tid < MT) {
        float ttv = ttc[tid];
        float acc = 0.0f;
        for (int t = 0; t < NT; ++t) {
            float dt = ttv - tcs[t];
            acc += expf(-dt*dt*ilt2) * Vts[j][t];
        }
        Acol[tid] = acc;
    }
    __syncthreads();

    // ---------- build + rank-8 factor + scale ----------
    float* Mp   = (float*)(smem + OFF_MP);
    auto   Pr   = (float (*)[LDW])(smem + OFF_PR);
    float* invs = (float*)(smem + OFF_INVS);
    float* dvs  = (float*)(smem + OFF_DVS);
    float wtj = wtjs[0];
    float nv = expf(lnv[0]);
    float ill2 = expf(-2.0f * lll[0]);
    float ile2 = expf(-2.0f * lle[0]);
    for (int idx = tid; idx < NS*LDW; idx += NTHR) {
        int r = idx / LDW, c = idx - r*LDW;
        int rbase = r & ~3;
        if (c < rbase) continue;
        float v;
        if (c < NS) {
            float d0 = scs[r*3+0] - scs[c*3+0];
            float d1 = scs[r*3+1] - scs[c*3+1];
            float d2 = scs[r*3+2] - scs[c*3+2];
            v = wtj * expf(-((d0*d0 + d1*d1)*ill2 + d2*d2*ile2));
            if (c == r) v += wtj * JITTER + nv;   // spatial jitter rides wtj
        } else if (c == NS) {
            v = gv[r];
        } else {
            v = 0.0f;
        }
        Mp[rs_off(r) + c - rbase] = v;
    }
    __syncthreads();
    for (int k0 = 0; k0 < NS - 1; k0 += 8) {
        int P = NS - k0; if (P > 8) P = 8;
        int W4 = (LDW - k0) >> 2;
        if (tid < W4) {
            int off[8];
            #pragma unroll
            for (int i = 0; i < 8; ++i)
                off[i] = (i < P) ? (rs_off(k0 + i) - ((i >= 4) ? 4 : 0)) : 0;
            float Bm[8][8];
            #pragma unroll
            for (int i = 0; i < 8; ++i) {
                #pragma unroll
                for (int c = 0; c < 8; ++c)
                    Bm[i][c] = (i < P && c >= i) ? Mp[off[i] + c]
                                                 : ((c == i) ? 1.0f : 0.0f);
            }
            float Lf[8][8]; float iv[8];
            #pragma unroll
            for (int k = 0; k < 8; ++k) {
                iv[k] = 1.0f / Bm[k][k];
                #pragma unroll
                for (int i = k + 1; i < 8; ++i) {
                    float l = Bm[k][i] * iv[k];
                    Lf[i][k] = l;
                    #pragma unroll
                    for (int c = i; c < 8; ++c) Bm[i][c] -= l * Bm[k][c];
                }
            }
            if (tid == 0) {
                #pragma unroll
                for (int i = 0; i < 8; ++i) invs[i] = iv[i];
            }
            int C = tid << 2;
            float4 m[8];
            #pragma unroll
            for (int i = 0; i < 8; ++i) {
                bool ok = (i < P) && (i < 4 || C >= 4);
                m[i] = ok ? *(float4*)&Mp[off[i] + C] : make_float4(0,0,0,0);
            }
            #pragma unroll
            for (int i = 1; i < 8; ++i) {
                #pragma unroll
                for (int k = 0; k < i; ++k) {
                    float l = Lf[i][k];
                    m[i].x -= l*m[k].x; m[i].y -= l*m[k].y;
                    m[i].z -= l*m[k].z; m[i].w -= l*m[k].w;
                }
            }
            #pragma unroll
            for (int i = 0; i < 8; ++i) *(float4*)&Pr[i][C] = m[i];
        }
        __syncthreads();
        for (int r = k0 + 1 + tid; r < NS; r += NTHR) {
            int rc = r - k0;
            float f[8];
            #pragma unroll
            for (int i = 0; i < 8; ++i)
                f[i] = (rc > i && i < P) ? Pr[i][rc] * invs[i] : 0.0f;
            int rbase = r & ~3;
            int ro = rs_off(r) - rbase;
            for (int C = rbase; C < LDW; C += 4) {
                int pc = C - k0;
                float4 v = *(float4*)&Mp[ro + C];
                #pragma unroll
                for (int i = 0; i < 8; ++i) {
                    float4 p = *(float4*)&Pr[i][pc];
                    v.x -= f[i]*p.x; v.y -= f[i]*p.y;
                    v.z -= f[i]*p.z; v.w -= f[i]*p.w;
                }
                *(float4*)&Mp[ro + C] = v;
            }
        }
        __syncthreads();
    }
    for (int r = tid; r < NS; r += NTHR)
        dvs[r] = rsqrtf(Mp[rs_off(r) + r - (r & ~3)]);
    __syncthreads();
    for (int idx = tid; idx < NS*LDW; idx += NTHR) {
        int r = idx / LDW, c = idx - r*LDW;
        int rbase = r & ~3;
        if (c < rbase) continue;
        int t = rs_off(r) + c - rbase;
        float dvr = dvs[r];
        if (c == r) Mp[t] = dvr;
        else if (c > r) Mp[t] *= dvr;
    }
    __syncthreads();
    // write scaled packed U (+ y in col 150) and Acol to workspace
    for (int t4 = tid * 4; t4 < NPACK; t4 += NTHR * 4)
        *(float4*)&Ug[(size_t)j*NPACK + t4] = *(float4*)&Mp[t4];
    if (tid < MT) AcolG[j*MT + tid] = Acol[tid];
}

// K2: 160 blocks (j, 50-col group) x 64 threads — one wave owns the CU's LDS
// pipe (4x less redundant broadcast traffic than fused). Forward solve with
// u[] in registers, then atomicAdd rank-1 epilogue (sigv added by j==0).
__global__ void __launch_bounds__(64) trsm_ep(
        const float* __restrict__ Ug, const float* __restrict__ AcolG,
        const float* __restrict__ sc, const float* __restrict__ tsc,
        const float* __restrict__ lll, const float* __restrict__ lle,
        const float* __restrict__ lsv, float* __restrict__ out) {
    __shared__ __align__(16) float Up[NPACK];
    __shared__ float scs[NS*3 + 2];
    __shared__ float AcolS[MT];
    int bid = blockIdx.x;
    int j = bid >> 2, grp = bid & 3;
    int lane = threadIdx.x;
    for (int t4 = lane * 4; t4 < NPACK; t4 += 256)
        *(float4*)&Up[t4] = *(const float4*)&Ug[(size_t)j*NPACK + t4];
    for (int t = lane; t < NS*3; t += 64) scs[t] = sc[t];
    if (lane < MT) AcolS[lane] = AcolG[j*MT + lane];
    __syncthreads();
    float ill2 = expf(-2.0f * lll[0]);
    float ile2 = expf(-2.0f * lle[0]);
    int c = grp * 50 + lane;
    bool active = (lane < 50);
    int cc = active ? c : 0;
    float tx = tsc[cc*3+0], ty = tsc[cc*3+1], tz = tsc[cc*3+2];
    float u[LDW];
    #pragma unroll
    for (int k = 0; k < NS; ++k) {
        float d0 = tx - scs[k*3+0];
        float d1 = ty - scs[k*3+1];
        float d2 = tz - scs[k*3+2];
        u[k] = expf(-((d0*d0 + d1*d1)*ill2 + d2*d2*ile2));
    }
    u[150] = 0.0f; u[151] = 0.0f;
    float qa = 0.0f, ra = 0.0f;
    #pragma unroll
    for (int k = 0; k < NS; ++k) {
        const int base = rs_off(k) - (k & ~3);
        float uk = u[k] * Up[base + k];      // diag slot = 1/d
        qa += uk * uk;
        ra += uk * Up[base + 150];           // scaled RHS = y_k
        const int kp = k + 1;
        const int ka = (kp + 3) & ~3;
        #pragma unroll
        for (int t = kp; t < ((ka < NS) ? ka : NS); ++t)
            u[t] -= Up[base + t] * uk;
        #pragma unroll
        for (int t = ka; t < NS; t += 4) {
            float4 w = *(const float4*)&Up[base + t];
            u[t+0] -= w.x * uk; u[t+1] -= w.y * uk;
            u[t+2] -= w.z * uk; u[t+3] -= w.w * uk;
        }
    }
    if (active) {
        float sigv = expf(lsv[0]);
        #pragma unroll
        for (int it = 0; it < MT; ++it) {
            float a = AcolS[it];
            atomicAdd(&out[c*MT + it], a * ra);
            float c2 = -a * a * qa;
            if (j == 0) c2 += sigv;
            atomicAdd(&out[MS*MT + c*MT + it], c2);
        }
    }
}

extern "C" void kernel_launch(void* const* d_in, const int* in_sizes, int n_in,
                              void* d_out, int out_size, void* d_ws, size_t ws_size,
                              hipStream_t stream) {
    const float* sc  = (const float*)d_in[0];   // 150x3
    const float* tc  = (const float*)d_in[1];   // 40x1
    const float* st  = (const float*)d_in[2];   // 150x40
    const float* tsc = (const float*)d_in[3];   // 200x3
    const float* ttc = (const float*)d_in[4];   // 30x1
    const float* lll = (const float*)d_in[5];
    const float* lle = (const float*)d_in[6];
    const float* llt = (const float*)d_in[7];
    const float* lnv = (const float*)d_in[8];
    const float* lsv = (const float*)d_in[9];
    float* out = (float*)d_out;

    float* ws    = (float*)d_ws;
    float* Ug    = ws;                      // 40*11848 = 473920
    float* AcolG = Ug + (size_t)NT*NPACK;   // 1200

    hipMemsetAsync(out, 0, (size_t)out_size * sizeof(float), stream);
    hipLaunchKernelGGL(gp_factor, dim3(NT), dim3(NTHR), 0, stream,
                       sc, tc, st, ttc, lll, lle, llt, lnv, Ug, AcolG);
    hipLaunchKernelGGL(trsm_ep, dim3(NT*4), dim3(64), 0, stream,
                       Ug, AcolG, sc, tsc, lll, lle, lsv, out);
}

// Round 19
// 419.049 us; speedup vs baseline: 1.2328x; 1.2328x over previous
//
#include <hip/hip_runtime.h>
#include <math.h>

#define NS 150
#define LDW 152
#define NPACK 11848   // packed upper-tri floats (rows 16B-aligned)
#define NT 40
#define MS 200
#define MT 30
#define N_SWEEPS 6
#define ROUNDS (N_SWEEPS*(NT-1))
#define JITTER 0.1f
#define NTHR 512

// ---- LDS union layout (bytes) ----
#define OFF_MP    0        // 47392
#define OFF_PR    47392    // 8*152*4 = 4864 -> 52256
#define OFF_INVS  52256    // 32 -> 52288
#define OFF_DVS   52288    // 600 -> 52896 (pad)
#define OFF_SCS   52896    // 1800 -> 54704 (pad)
#define OFF_TSCS  54704    // 2400 -> 57104
#define OFF_QV    57104    // 800 -> 57904
#define OFF_RV    57904    // 800 -> 58704
#define OFF_GV    58704    // 600 -> 59304
#define OFF_ACOL  59304    // 120 -> 59424
#define OFF_WTJ   59424    // 4  -> 59428
#define SMEM_BYTES 59440
// jacobi-phase overlay (inside Mp region only):
#define OFF_A2    0        // 2*40*41*4 = 13120
#define OFF_VTS   13120    // 40*44*4 = 7040 -> 20160
#define OFF_PRM   20160    // 8*20*16 = 2560 -> 22720
#define OFF_TCS   22720    // 160 -> 22880   (< OFF_PR; gv/Acol/wtj live above)

// packed upper-tri storage: row r holds cols [r&~3, 152), 16B-aligned start.
__device__ __forceinline__ int rs_off(int r) {
    int g = r >> 2, rm = r & 3;
    return LDW * r - 8 * g * (g - 1) - 4 * rm * g;
}

__device__ __forceinline__ void jac_params(const float (*A)[NT+1], float4* dst,
                                           int i, int rr) {
    int i0 = i, i1 = NT - 1 - i;
    int p = (i0 == 0) ? 0 : ((i0 - 1 + rr) % (NT - 1)) + 1;
    int q = ((i1 - 1 + rr) % (NT - 1)) + 1;
    if (p > q) { int tsw = p; p = q; q = tsw; }
    float app = A[p][p], aqq = A[q][q], apq = A[p][q];
    float c, s;
    if (apq == 0.0f) { c = 1.0f; s = 0.0f; }
    else {
        float tau = (aqq - app) / (2.0f * apq);
        float tt = ((tau >= 0.0f) ? 1.0f : -1.0f) / (fabsf(tau) + sqrtf(1.0f + tau*tau));
        c = rsqrtf(1.0f + tt*tt);
        s = tt * c;
    }
    dst[i] = make_float4(c, s, __int_as_float(p), __int_as_float(q));
}

// ONE kernel, 40 blocks x 512 threads (R14/R17 configuration — measured
// optimum, 418 µs total, reproduced twice). Per block: redundant Jacobi
// (1 barrier/round, per-wave redundant params, all 8 waves) -> extract
// (wt_j, g_j, Acol_j) -> packed M_j build -> rank-8 panel factorization ->
// in-LDS scale -> fused 4-wave trsm -> atomicAdd epilogue into zeroed out.
//
// Structural notes from this session (MI355X):
//  - NEVER shrink a barriered/iterative LDS loop below ~4 waves: exposed
//    LDS latency >> barrier cost (R4 295->451, R15 351->838, R18 trsm
//    70->165 µs all confirmed this).
//  - Any work added to the barrier-loop critical-path wave is serial time
//    (R16 folded prefill: +30 µs).
//  - Lane-address spread beats lane-count utilization on the LDS pipe
//    (R12 packed-chunk phase B: conflicts 1.19M->1.85M, +210 µs).
//  - absmax is Jacobi-convergence-limited: sweeps 10/8/6/5 ->
//    0.0039/0.0078/0.0117/0.0508; threshold 0.0322 -> 6 sweeps required.
//  - Harness fixed overhead ~66 µs regardless of kernel count.
__global__ void __launch_bounds__(NTHR, 1) gp_block(
        const float* __restrict__ sc,  const float* __restrict__ tc,
        const float* __restrict__ st,  const float* __restrict__ tsc,
        const float* __restrict__ ttc,
        const float* __restrict__ lll, const float* __restrict__ lle,
        const float* __restrict__ llt, const float* __restrict__ lnv,
        const float* __restrict__ lsv, float* __restrict__ out) {
    __shared__ __align__(16) char smem[SMEM_BYTES];
    int j = blockIdx.x, tid = threadIdx.x;

    auto A2   = (float (*)[NT][NT+1])(smem + OFF_A2);
    auto Vts  = (float (*)[44])(smem + OFF_VTS);
    auto prm  = (float4 (*)[NT/2])(smem + OFF_PRM);
    float* tcs  = (float*)(smem + OFF_TCS);
    float* gv   = (float*)(smem + OFF_GV);
    float* Acol = (float*)(smem + OFF_ACOL);
    float* wtjs = (float*)(smem + OFF_WTJ);
    float* scs  = (float*)(smem + OFF_SCS);
    float* tscs = (float*)(smem + OFF_TSCS);

    float ilt2 = expf(-2.0f * llt[0]);
    if (tid < NT) tcs[tid] = tc[tid];
    // hoist coord staging (disjoint LDS; latency hides under Jacobi)
    for (int t = tid; t < NS*3; t += NTHR) scs[t] = sc[t];
    for (int t = tid; t < MS*3; t += NTHR) tscs[t] = tsc[t];
    __syncthreads();
    for (int idx = tid; idx < NT*NT; idx += NTHR) {
        int i = idx / NT, jj = idx - i*NT;
        float dt = tcs[i] - tcs[jj];
        float v = expf(-dt*dt*ilt2);
        if (i == jj) v += JITTER;
        A2[0][i][jj] = v;
    }
    for (int idx = tid; idx < NT*44; idx += NTHR) {
        int jr = idx / 44, k = idx - jr*44;
        Vts[jr][k] = (jr == k) ? 1.0f : 0.0f;
    }
    __syncthreads();
    int wave = tid >> 6, lane = tid & 63;
    for (int rd = 0; rd < ROUNDS; ++rd) {
        int cur = rd & 1, nxt = cur ^ 1;
        float4* wp = prm[wave];
        if (lane < NT/2) jac_params(A2[cur], wp, lane, rd % (NT - 1));
        __builtin_amdgcn_wave_barrier();   // same-wave LDS in-order; pin compiler
        for (int t = tid; t < 600; t += NTHR) {
            if (t < 400) {
                int bi = t / 20, bj = t - bi*20;
                float4 Pi = wp[bi], Pj = wp[bj];
                int pi = __float_as_int(Pi.z), qi = __float_as_int(Pi.w);
                int pj = __float_as_int(Pj.z), qj = __float_as_int(Pj.w);
                float ci = Pi.x, si = Pi.y, cj = Pj.x, sj = Pj.y;
                float a00 = A2[cur][pi][pj], a01 = A2[cur][pi][qj];
                float a10 = A2[cur][qi][pj], a11 = A2[cur][qi][qj];
                float b00 = ci*a00 - si*a10, b01 = ci*a01 - si*a11;
                float b10 = si*a00 + ci*a10, b11 = si*a01 + ci*a11;
                A2[nxt][pi][pj] = cj*b00 - sj*b01; A2[nxt][pi][qj] = sj*b00 + cj*b01;
                A2[nxt][qi][pj] = cj*b10 - sj*b11; A2[nxt][qi][qj] = sj*b10 + cj*b11;
            } else {
                int u2 = t - 400;
                int pr = u2 / 10, ch = (u2 - pr*10) << 2;
                float4 P = wp[pr];
                int pj = __float_as_int(P.z), qj = __float_as_int(P.w);
                float c = P.x, s = P.y;
                float4 vp = *(float4*)&Vts[pj][ch];
                float4 vq = *(float4*)&Vts[qj][ch];
                float4 np, nq;
                np.x = c*vp.x - s*vq.x; nq.x = s*vp.x + c*vq.x;
                np.y = c*vp.y - s*vq.y; nq.y = s*vp.y + c*vq.y;
                np.z = c*vp.z - s*vq.z; nq.z = s*vp.z + c*vq.z;
                np.w = c*vp.w - s*vq.w; nq.w = s*vp.w + c*vq.w;
                *(float4*)&Vts[pj][ch] = np;
                *(float4*)&Vts[qj][ch] = nq;
            }
        }
        __syncthreads();
    }
    const int fin = ROUNDS & 1;
    if (tid == 0) wtjs[0] = A2[fin][j][j];
    for (int s = tid; s < NS; s += NTHR) {
        const float4* va = (const float4*)&Vts[j][0];
        const float4* sa = (const float4*)&st[s*NT];
        float acc = 0.0f;
        #pragma unroll
        for (int c4 = 0; c4 < NT/4; ++c4) {
            float4 a = va[c4], b = sa[c4];
            acc += a.x*b.x + a.y*b.y + a.z*b.z + a.w*b.w;
        }
        gv[s] = acc;
    }
    if (tid < MT) {
        float ttv = ttc[tid];
        float acc = 0.0f;
        for (int t = 0; t < NT; ++t) {
            float dt = ttv - tcs[t];
            acc += expf(-dt*dt*ilt2) * Vts[j][t];
        }
        Acol[tid] = acc;
    }
    __syncthreads();

    // ---------- phase 2: build + rank-8 factor + scale + trsm ----------
    float* Mp   = (float*)(smem + OFF_MP);
    auto   Pr   = (float (*)[LDW])(smem + OFF_PR);
    float* invs = (float*)(smem + OFF_INVS);
    float* dvs  = (float*)(smem + OFF_DVS);
    float* qv   = (float*)(smem + OFF_QV);
    float* Rv   = (float*)(smem + OFF_RV);
    float wtj = wtjs[0];
    float nv = expf(lnv[0]);
    float ill2 = expf(-2.0f * lll[0]);
    float ile2 = expf(-2.0f * lle[0]);
    for (int idx = tid; idx < NS*LDW; idx += NTHR) {
        int r = idx / LDW, c = idx - r*LDW;
        int rbase = r & ~3;
        if (c < rbase) continue;
        float v;
        if (c < NS) {
            float d0 = scs[r*3+0] - scs[c*3+0];
            float d1 = scs[r*3+1] - scs[c*3+1];
            float d2 = scs[r*3+2] - scs[c*3+2];
            v = wtj * expf(-((d0*d0 + d1*d1)*ill2 + d2*d2*ile2));
            if (c == r) v += wtj * JITTER + nv;   // spatial jitter rides wtj
        } else if (c == NS) {
            v = gv[r];
        } else {
            v = 0.0f;
        }
        Mp[rs_off(r) + c - rbase] = v;
    }
    __syncthreads();
    for (int k0 = 0; k0 < NS - 1; k0 += 8) {
        int P = NS - k0; if (P > 8) P = 8;
        int W4 = (LDW - k0) >> 2;
        // phase A (single wave): redundant 8x8 elimination + chunk pre-elim -> Pr
        if (tid < W4) {
            int off[8];
            #pragma unroll
            for (int i = 0; i < 8; ++i)
                off[i] = (i < P) ? (rs_off(k0 + i) - ((i >= 4) ? 4 : 0)) : 0;
            float Bm[8][8];
            #pragma unroll
            for (int i = 0; i < 8; ++i) {
                #pragma unroll
                for (int c = 0; c < 8; ++c)
                    Bm[i][c] = (i < P && c >= i) ? Mp[off[i] + c]
                                                 : ((c == i) ? 1.0f : 0.0f);
            }
            float Lf[8][8]; float iv[8];
            #pragma unroll
            for (int k = 0; k < 8; ++k) {
                iv[k] = 1.0f / Bm[k][k];
                #pragma unroll
                for (int i = k + 1; i < 8; ++i) {
                    float l = Bm[k][i] * iv[k];
                    Lf[i][k] = l;
                    #pragma unroll
                    for (int c = i; c < 8; ++c) Bm[i][c] -= l * Bm[k][c];
                }
            }
            if (tid == 0) {
                #pragma unroll
                for (int i = 0; i < 8; ++i) invs[i] = iv[i];
            }
            int C = tid << 2;
            float4 m[8];
            #pragma unroll
            for (int i = 0; i < 8; ++i) {
                bool ok = (i < P) && (i < 4 || C >= 4);
                m[i] = ok ? *(float4*)&Mp[off[i] + C] : make_float4(0,0,0,0);
            }
            #pragma unroll
            for (int i = 1; i < 8; ++i) {
                #pragma unroll
                for (int k = 0; k < i; ++k) {
                    float l = Lf[i][k];
                    m[i].x -= l*m[k].x; m[i].y -= l*m[k].y;
                    m[i].z -= l*m[k].z; m[i].w -= l*m[k].w;
                }
            }
            #pragma unroll
            for (int i = 0; i < 8; ++i) *(float4*)&Pr[i][C] = m[i];
        }
        __syncthreads();
        // phase B: rank-8 trailing update, thread-per-row, contiguous f4 sweep
        for (int r = k0 + 1 + tid; r < NS; r += NTHR) {
            int rc = r - k0;
            float f[8];
            #pragma unroll
            for (int i = 0; i < 8; ++i)
                f[i] = (rc > i && i < P) ? Pr[i][rc] * invs[i] : 0.0f;
            int rbase = r & ~3;
            int ro = rs_off(r) - rbase;
            for (int C = rbase; C < LDW; C += 4) {
                int pc = C - k0;
                float4 v = *(float4*)&Mp[ro + C];
                #pragma unroll
                for (int i = 0; i < 8; ++i) {
                    float4 p = *(float4*)&Pr[i][pc];
                    v.x -= f[i]*p.x; v.y -= f[i]*p.y;
                    v.z -= f[i]*p.z; v.w -= f[i]*p.w;
                }
                *(float4*)&Mp[ro + C] = v;
            }
        }
        __syncthreads();
    }
    // scale in place: diag slot = 1/d, cols>r (incl. RHS col 150 -> y) *= 1/d
    for (int r = tid; r < NS; r += NTHR)
        dvs[r] = rsqrtf(Mp[rs_off(r) + r - (r & ~3)]);
    __syncthreads();
    for (int idx = tid; idx < NS*LDW; idx += NTHR) {
        int r = idx / LDW, c = idx - r*LDW;
        int rbase = r & ~3;
        if (c < rbase) continue;
        int t = rs_off(r) + c - rbase;
        float dvr = dvs[r];
        if (c == r) Mp[t] = dvr;
        else if (c > r) Mp[t] *= dvr;
    }
    __syncthreads();
    // fused trsm: thread-per-test-column, u[] in registers (152 w/ zero tail)
    if (tid < MS) {
        float tx = tscs[tid*3+0], ty = tscs[tid*3+1], tz = tscs[tid*3+2];
        float u[LDW];
        #pragma unroll
        for (int k = 0; k < NS; ++k) {
            float d0 = tx - scs[k*3+0];
            float d1 = ty - scs[k*3+1];
            float d2 = tz - scs[k*3+2];
            u[k] = expf(-((d0*d0 + d1*d1)*ill2 + d2*d2*ile2));
        }
        u[150] = 0.0f; u[151] = 0.0f;
        float qa = 0.0f, ra = 0.0f;
        #pragma unroll
        for (int k = 0; k < NS; ++k) {
            const int base = rs_off(k) - (k & ~3);
            float uk = u[k] * Mp[base + k];     // diag slot = 1/d
            qa += uk * uk;
            ra += uk * Mp[base + 150];          // scaled RHS = y_k
            const int kp = k + 1;
            const int ka = (kp + 3) & ~3;
            #pragma unroll
            for (int t = kp; t < ((ka < NS) ? ka : NS); ++t)
                u[t] -= Mp[base + t] * uk;
            #pragma unroll
            for (int t = ka; t < NS; t += 4) {
                float4 w = *(const float4*)&Mp[base + t];
                u[t+0] -= w.x * uk; u[t+1] -= w.y * uk;
                u[t+2] -= w.z * uk; u[t+3] -= w.w * uk;
            }
        }
        qv[tid] = qa;
        Rv[tid] = ra;
    }
    __syncthreads();

    // ---------- phase 3: atomic rank-1 accumulation into out ----------
    float sigv = expf(lsv[0]);
    for (int idx = tid; idx < MS*MT; idx += NTHR) {
        int is = idx / MT, it = idx - is*MT;
        float a = Acol[it];
        atomicAdd(&out[idx], a * Rv[is]);
        float c2 = -a * a * qv[is];
        if (j == 0) c2 += sigv;
        atomicAdd(&out[MS*MT + idx], c2);
    }
}

extern "C" void kernel_launch(void* const* d_in, const int* in_sizes, int n_in,
                              void* d_out, int out_size, void* d_ws, size_t ws_size,
                              hipStream_t stream) {
    const float* sc  = (const float*)d_in[0];   // 150x3
    const float* tc  = (const float*)d_in[1];   // 40x1
    const float* st  = (const float*)d_in[2];   // 150x40
    const float* tsc = (const float*)d_in[3];   // 200x3
    const float* ttc = (const float*)d_in[4];   // 30x1
    const float* lll = (const float*)d_in[5];
    const float* lle = (const float*)d_in[6];
    const float* llt = (const float*)d_in[7];
    const float* lnv = (const float*)d_in[8];
    const float* lsv = (const float*)d_in[9];
    float* out = (float*)d_out;

    hipMemsetAsync(out, 0, (size_t)out_size * sizeof(float), stream);
    hipLaunchKernelGGL(gp_block, dim3(NT), dim3(NTHR), 0, stream,
                       sc, tc, st, tsc, ttc, lll, lle, llt, lnv, lsv, out);
}